// Round 1
// baseline (3579.802 us; speedup 1.0000x reference)
//
#include <hip/hip_runtime.h>
#include <math.h>

#define BB 4096
#define N_TOT 12288
#define DMEM 128
#define DMSG 384
#define DTIME 100
#define DKIN 484
#define MSZ 10
#define E_EDGES 81920
#define NUNIQ 50000

__device__ __forceinline__ float wredsum(float v) {
#pragma unroll
  for (int off = 32; off > 0; off >>= 1) v += __shfl_down(v, off, 64);
  return __shfl(v, 0, 64);
}

__device__ __forceinline__ void softmax10(const float* lg, float* w) {
  float v[10];
#pragma unroll
  for (int m = 0; m < 10; ++m) { float x = lg[m]; v[m] = x > 0.f ? x : 0.2f * x; }
  float mx = -1e30f;
#pragma unroll
  for (int m = 0; m < 10; ++m) mx = fmaxf(mx, v[m]);
  float s = 0.f;
#pragma unroll
  for (int m = 0; m < 10; ++m) { v[m] = expf(v[m] - mx); s += v[m]; }
  float inv = 1.f / s;
#pragma unroll
  for (int m = 0; m < 10; ++m) w[m] = v[m] * inv;
}

// One wave per block; 2 batch rows per block. Lane l owns output cols
// {l, l+64} of K and {l, l+64} of V for both rows (80 accumulators).
__global__ __launch_bounds__(64) void k_memupd(
    const int* __restrict__ nodes, const float* __restrict__ times,
    const float* __restrict__ mem_table, const float* __restrict__ mail_table,
    const float* __restrict__ mail_time,
    const float* __restrict__ wq_w, const float* __restrict__ wq_b,
    const float* __restrict__ wk_w, const float* __restrict__ wk_b,
    const float* __restrict__ wv_w, const float* __restrict__ wv_b,
    const float* __restrict__ mlp_w, const float* __restrict__ mlp_b,
    const float* __restrict__ ln_g, const float* __restrict__ ln_b,
    const float* __restrict__ te_w, const float* __restrict__ te_b,
    float* __restrict__ mem_out)
{
  const int l = threadIdx.x;
  const int n0 = blockIdx.x * 2;
  __shared__ __align__(16) float tfeat_s[2][MSZ][DTIME];
  __shared__ __align__(16) float mem_s[2][DMEM];
  __shared__ __align__(16) float ln_s[2][DMEM];

  int nodeid[2];
  nodeid[0] = nodes[n0];
  nodeid[1] = nodes[n0 + 1];

  // ---- stage mem rows + time features ----
#pragma unroll
  for (int nn = 0; nn < 2; ++nn) {
    const int node = nodeid[nn];
    mem_s[nn][l]      = mem_table[(size_t)node * DMEM + l];
    mem_s[nn][l + 64] = mem_table[(size_t)node * DMEM + l + 64];
    const float tn = times[n0 + nn];
    for (int idx = l; idx < MSZ * DTIME; idx += 64) {
      int m = idx / DTIME, j = idx - m * DTIME;
      float dt = tn - mail_time[(size_t)node * MSZ + m];
      tfeat_s[nn][m][j] = cosf(dt * te_w[j] + te_b[j]);
    }
  }
  __syncthreads();

  // ---- Q = mem @ wq_w + wq_b (lane cols l, l+64) ----
  float q0[2], q1[2];
#pragma unroll
  for (int nn = 0; nn < 2; ++nn) {
    float a0 = wq_b[l], a1 = wq_b[l + 64];
    for (int i = 0; i < DMEM; i += 4) {
      float4 mm = *(const float4*)&mem_s[nn][i];
      const float* w = wq_w + (size_t)i * DMEM;
      a0 += mm.x * w[l]       + mm.y * w[DMEM + l]       + mm.z * w[2*DMEM + l]       + mm.w * w[3*DMEM + l];
      a1 += mm.x * w[l + 64]  + mm.y * w[DMEM + l + 64]  + mm.z * w[2*DMEM + l + 64]  + mm.w * w[3*DMEM + l + 64];
    }
    q0[nn] = a0; q1[nn] = a1;
  }

  // ---- K/V projection ----
  float aK0[2][10], aK1[2][10], aV0[2][10], aV1[2][10];
#pragma unroll
  for (int nn = 0; nn < 2; ++nn)
#pragma unroll
    for (int m = 0; m < 10; ++m) {
      aK0[nn][m] = wk_b[l];      aK1[nn][m] = wk_b[l + 64];
      aV0[nn][m] = wv_b[l];      aV1[nn][m] = wv_b[l + 64];
    }

  const float* mailp[2];
  mailp[0] = mail_table + (size_t)nodeid[0] * (MSZ * DMSG);
  mailp[1] = mail_table + (size_t)nodeid[1] * (MSZ * DMSG);

  // msg part of the K-dim (i in [0,384)), A read straight from global (uniform addr)
  for (int i = 0; i < DMSG; i += 4) {
    float wk0[4], wk1[4], wv0[4], wv1[4];
#pragma unroll
    for (int t = 0; t < 4; ++t) {
      const float* wkp = wk_w + (size_t)(i + t) * DMEM;
      const float* wvp = wv_w + (size_t)(i + t) * DMEM;
      wk0[t] = wkp[l]; wk1[t] = wkp[l + 64];
      wv0[t] = wvp[l]; wv1[t] = wvp[l + 64];
    }
#pragma unroll
    for (int nn = 0; nn < 2; ++nn) {
      const float* mp = mailp[nn];
#pragma unroll
      for (int m = 0; m < 10; ++m) {
        float4 a = *(const float4*)(mp + m * DMSG + i);
        aK0[nn][m] += a.x * wk0[0] + a.y * wk0[1] + a.z * wk0[2] + a.w * wk0[3];
        aK1[nn][m] += a.x * wk1[0] + a.y * wk1[1] + a.z * wk1[2] + a.w * wk1[3];
        aV0[nn][m] += a.x * wv0[0] + a.y * wv0[1] + a.z * wv0[2] + a.w * wv0[3];
        aV1[nn][m] += a.x * wv1[0] + a.y * wv1[1] + a.z * wv1[2] + a.w * wv1[3];
      }
    }
  }
  // tfeat part (i in [384,484)), A from LDS broadcast
  for (int i = 0; i < DTIME; i += 4) {
    float wk0[4], wk1[4], wv0[4], wv1[4];
#pragma unroll
    for (int t = 0; t < 4; ++t) {
      const float* wkp = wk_w + (size_t)(DMSG + i + t) * DMEM;
      const float* wvp = wv_w + (size_t)(DMSG + i + t) * DMEM;
      wk0[t] = wkp[l]; wk1[t] = wkp[l + 64];
      wv0[t] = wvp[l]; wv1[t] = wvp[l + 64];
    }
#pragma unroll
    for (int nn = 0; nn < 2; ++nn) {
#pragma unroll
      for (int m = 0; m < 10; ++m) {
        float4 a = *(const float4*)&tfeat_s[nn][m][i];
        aK0[nn][m] += a.x * wk0[0] + a.y * wk0[1] + a.z * wk0[2] + a.w * wk0[3];
        aK1[nn][m] += a.x * wk1[0] + a.y * wk1[1] + a.z * wk1[2] + a.w * wk1[3];
        aV0[nn][m] += a.x * wv0[0] + a.y * wv0[1] + a.z * wv0[2] + a.w * wv0[3];
        aV1[nn][m] += a.x * wv1[0] + a.y * wv1[1] + a.z * wv1[2] + a.w * wv1[3];
      }
    }
  }

  // ---- attention + residual + LayerNorm ----
#pragma unroll
  for (int nn = 0; nn < 2; ++nn) {
    float lg0[10], lg1[10];
#pragma unroll
    for (int m = 0; m < 10; ++m) {
      lg0[m] = wredsum(q0[nn] * aK0[nn][m]);   // head 0: cols 0..63
      lg1[m] = wredsum(q1[nn] * aK1[nn][m]);   // head 1: cols 64..127
    }
    float w0[10], w1[10];
    softmax10(lg0, w0);
    softmax10(lg1, w1);
    float o0 = mem_s[nn][l], o1 = mem_s[nn][l + 64];
#pragma unroll
    for (int m = 0; m < 10; ++m) {
      o0 += w0[m] * aV0[nn][m];
      o1 += w1[m] * aV1[nn][m];
    }
    float s  = wredsum(o0 + o1);
    float s2 = wredsum(o0 * o0 + o1 * o1);
    float mu  = s * (1.f / 128.f);
    float var = s2 * (1.f / 128.f) - mu * mu;
    float inv = rsqrtf(var + 1e-5f);
    ln_s[nn][l]      = (o0 - mu) * inv * ln_g[l]      + ln_b[l];
    ln_s[nn][l + 64] = (o1 - mu) * inv * ln_g[l + 64] + ln_b[l + 64];
  }
  __syncthreads();

  // ---- MLP + relu ----
#pragma unroll
  for (int nn = 0; nn < 2; ++nn) {
    float h0 = mlp_b[l], h1 = mlp_b[l + 64];
    for (int i = 0; i < DMEM; i += 4) {
      float4 y = *(const float4*)&ln_s[nn][i];
      const float* w = mlp_w + (size_t)i * DMEM;
      h0 += y.x * w[l]      + y.y * w[DMEM + l]      + y.z * w[2*DMEM + l]      + y.w * w[3*DMEM + l];
      h1 += y.x * w[l + 64] + y.y * w[DMEM + l + 64] + y.z * w[2*DMEM + l + 64] + y.w * w[3*DMEM + l + 64];
    }
    float* op = mem_out + (size_t)(n0 + nn) * DMEM;
    op[l]      = fmaxf(h0, 0.f);
    op[l + 64] = fmaxf(h1, 0.f);
  }
}

// link predictor: one wave per src row, computes pos and neg scores
__global__ __launch_bounds__(64) void k_pred(
    const float* __restrict__ mem_out,
    const float* __restrict__ src_w, const float* __restrict__ src_b,
    const float* __restrict__ dst_w, const float* __restrict__ dst_b,
    const float* __restrict__ out_w, const float* __restrict__ out_b,
    float* __restrict__ pos, float* __restrict__ negs)
{
  const int r = blockIdx.x, l = threadIdx.x;
  __shared__ __align__(16) float ss[DMEM], sd[DMEM], sn[DMEM];
  ss[l]      = mem_out[(size_t)r * DMEM + l];
  ss[l + 64] = mem_out[(size_t)r * DMEM + l + 64];
  sd[l]      = mem_out[((size_t)BB + r) * DMEM + l];
  sd[l + 64] = mem_out[((size_t)BB + r) * DMEM + l + 64];
  sn[l]      = mem_out[((size_t)2 * BB + r) * DMEM + l];
  sn[l + 64] = mem_out[((size_t)2 * BB + r) * DMEM + l + 64];
  __syncthreads();

  float hs0 = src_b[l], hs1 = src_b[l + 64];
  float hd0 = dst_b[l], hd1 = dst_b[l + 64];
  float hn0 = dst_b[l], hn1 = dst_b[l + 64];
  for (int i = 0; i < DMEM; i += 4) {
    const float* w  = src_w + (size_t)i * DMEM;
    const float* wd = dst_w + (size_t)i * DMEM;
    float4 a = *(const float4*)&ss[i];
    hs0 += a.x * w[l]      + a.y * w[DMEM + l]      + a.z * w[2*DMEM + l]      + a.w * w[3*DMEM + l];
    hs1 += a.x * w[l + 64] + a.y * w[DMEM + l + 64] + a.z * w[2*DMEM + l + 64] + a.w * w[3*DMEM + l + 64];
    float4 b = *(const float4*)&sd[i];
    hd0 += b.x * wd[l]      + b.y * wd[DMEM + l]      + b.z * wd[2*DMEM + l]      + b.w * wd[3*DMEM + l];
    hd1 += b.x * wd[l + 64] + b.y * wd[DMEM + l + 64] + b.z * wd[2*DMEM + l + 64] + b.w * wd[3*DMEM + l + 64];
    float4 c = *(const float4*)&sn[i];
    hn0 += c.x * wd[l]      + c.y * wd[DMEM + l]      + c.z * wd[2*DMEM + l]      + c.w * wd[3*DMEM + l];
    hn1 += c.x * wd[l + 64] + c.y * wd[DMEM + l + 64] + c.z * wd[2*DMEM + l + 64] + c.w * wd[3*DMEM + l + 64];
  }
  float ow0 = out_w[l], ow1 = out_w[l + 64];
  float p = fmaxf(hs0 + hd0, 0.f) * ow0 + fmaxf(hs1 + hd1, 0.f) * ow1;
  p = wredsum(p);
  float q = fmaxf(hs0 + hn0, 0.f) * ow0 + fmaxf(hs1 + hn1, 0.f) * ow1;
  q = wredsum(q);
  if (l == 0) {
    pos[r]  = p + out_b[0];
    negs[r] = q + out_b[0];
  }
}

// scatter-add of mail rows into segments (mail_rows materialized on the fly)
__global__ void k_scatter_mail(
    const float* __restrict__ mem_out, const float* __restrict__ efeat,
    const int* __restrict__ dstindex, const int* __restrict__ src_seg,
    float* __restrict__ mail_agg)
{
  int idx = blockIdx.x * blockDim.x + threadIdx.x;   // < E*384 exactly
  int e = idx / DMSG;
  int d = idx - e * DMSG;
  int r = dstindex[e];
  int seg = src_seg[e];
  float v;
  if (d < 128)       v = mem_out[(size_t)r * DMEM + d];
  else if (d < 256)  v = mem_out[(size_t)(r ^ BB) * DMEM + (d - 128)];
  else               v = efeat[(size_t)(r & (BB - 1)) * DMEM + (d - 256)];
  atomicAdd(&mail_agg[(size_t)seg * DMSG + d], v);
}

__global__ void k_scatter_cnt(
    const float* __restrict__ times, const int* __restrict__ dstindex,
    const int* __restrict__ src_seg, float* __restrict__ cnt,
    float* __restrict__ ts_agg)
{
  int e = blockIdx.x * blockDim.x + threadIdx.x;
  if (e < E_EDGES) {
    int seg = src_seg[e];
    atomicAdd(&cnt[seg], 1.0f);
    atomicAdd(&ts_agg[seg], times[dstindex[e]]);
  }
}

__global__ void k_finalize(const float* __restrict__ cnt,
                           float* __restrict__ mail_agg,
                           float* __restrict__ ts_agg)
{
  int idx = blockIdx.x * blockDim.x + threadIdx.x;
  if (idx >= NUNIQ * 385) return;
  int u = idx / 385;
  int j = idx - u * 385;
  float inv = 1.0f / fmaxf(cnt[u], 1.0f);
  if (j < DMSG) mail_agg[(size_t)u * DMSG + j] *= inv;
  else          ts_agg[u] *= inv;
}

extern "C" void kernel_launch(void* const* d_in, const int* in_sizes, int n_in,
                              void* d_out, int out_size, void* d_ws, size_t ws_size,
                              hipStream_t stream)
{
  const int*   nodes      = (const int*)d_in[0];
  const float* times      = (const float*)d_in[1];
  const float* mem_table  = (const float*)d_in[2];
  const float* mail_table = (const float*)d_in[3];
  const float* mail_time  = (const float*)d_in[4];
  const float* efeat      = (const float*)d_in[5];
  const float* wq_w = (const float*)d_in[6];
  const float* wq_b = (const float*)d_in[7];
  const float* wk_w = (const float*)d_in[8];
  const float* wk_b = (const float*)d_in[9];
  const float* wv_w = (const float*)d_in[10];
  const float* wv_b = (const float*)d_in[11];
  const float* mlp_w = (const float*)d_in[12];
  const float* mlp_b = (const float*)d_in[13];
  const float* ln_g  = (const float*)d_in[14];
  const float* ln_b  = (const float*)d_in[15];
  const float* te_w  = (const float*)d_in[16];
  const float* te_b  = (const float*)d_in[17];
  const float* src_w = (const float*)d_in[18];
  const float* src_b = (const float*)d_in[19];
  const float* dst_w = (const float*)d_in[20];
  const float* dst_b = (const float*)d_in[21];
  const float* out_w = (const float*)d_in[22];
  const float* out_b = (const float*)d_in[23];
  const int* dstindex = (const int*)d_in[24];
  const int* src_seg  = (const int*)d_in[25];

  float* out = (float*)d_out;
  float* mem_out  = out;                      // N*128            = 1,572,864
  float* pos      = out + 1572864;            // B                =     4,096
  float* negs     = out + 1576960;            // B                =     4,096
  float* mail_agg = out + 1581056;            // NUNIQ*384        = 19,200,000
  float* ts_agg   = out + 20781056;           // NUNIQ            =    50,000
  float* cnt      = (float*)d_ws;             // NUNIQ floats scratch

  hipMemsetAsync(cnt, 0, NUNIQ * sizeof(float), stream);
  hipMemsetAsync(mail_agg, 0, (size_t)(NUNIQ * DMSG + NUNIQ) * sizeof(float), stream);

  k_memupd<<<N_TOT / 2, 64, 0, stream>>>(
      nodes, times, mem_table, mail_table, mail_time,
      wq_w, wq_b, wk_w, wk_b, wv_w, wv_b, mlp_w, mlp_b,
      ln_g, ln_b, te_w, te_b, mem_out);

  k_pred<<<BB, 64, 0, stream>>>(mem_out, src_w, src_b, dst_w, dst_b,
                                out_w, out_b, pos, negs);

  k_scatter_mail<<<(E_EDGES * DMSG) / 256, 256, 0, stream>>>(
      mem_out, efeat, dstindex, src_seg, mail_agg);

  k_scatter_cnt<<<(E_EDGES + 255) / 256, 256, 0, stream>>>(
      times, dstindex, src_seg, cnt, ts_agg);

  k_finalize<<<(NUNIQ * 385 + 255) / 256, 256, 0, stream>>>(cnt, mail_agg, ts_agg);
}